// Round 11
// baseline (343.555 us; speedup 1.0000x reference)
//
#include <hip/hip_runtime.h>
#include <hip/hip_fp16.h>
#include <math.h>

// GCNII forward, fp16-compressed intermediates.
//   h0 = relu(x @ Wlin + b)                       [lin0: tiled GEMM, M_TILE=64]
//   per layer l: z = 0.9*(A@h) + 0.1*x0           [gather: CSR, group-per-node]
//                h = relu(z @ W'_l)               [dense: tiled GEMM, M_TILE=64]
//   W'_l = (1-beta_l) I + beta_l W_l (premixed).
// Round-11: M_TILE 128->64 for lin0/dense (round-10 counters: occupancy 22%
// was GRID-limited at 782 blocks; 1563 blocks ~6/CU). W from global (L1).
// x/z tile in 8KB XOR-swizzled LDS. Gather stages 32 records/group (was 16)
// for deeper gather batching.
// CSR build: bucketed counting sort (no random sub-line global stores).
// Constants: N=100000, E=1600000, H=128, D=64, L=4.

#define DD 64
#define HH 128
#define M_TILE 64
#define K_CHUNK 32
#define NPB 128            // nodes per bucket (bucket = node>>7)
#define SLOT 2560          // record slots per bucket (mean ~2046, +11 sigma)
#define NBUK_MAX 1024
#define PART_BLOCKS 256
#define PART_THREADS 1024

__device__ inline ushort f2h(float f) { return __half_as_ushort(__float2half(f)); }
__device__ inline float us2f(ushort u) { return __half2float(__ushort_as_half(u)); }

__global__ __launch_bounds__(256) void init_bcur(int* bcur, int nbuk) {
    int i = blockIdx.x * blockDim.x + threadIdx.x;
    if (i < nbuk) bcur[i] = i * SLOT;
}

// One-pass partition into bucket slots. Record: {row:17 | col_lo15:15},
// {col_hi2:2 | w_fp16:16<<2}.
__global__ __launch_bounds__(PART_THREADS) void partition_kernel(
    const int* __restrict__ row, const int* __restrict__ col,
    const float* __restrict__ ew, int* __restrict__ bcur,
    uint2* __restrict__ pk, int E, int nbuk) {
    __shared__ int cnt[NBUK_MAX], base[NBUK_MAX], rc[NBUK_MAX];
    int t = threadIdx.x;
    for (int i = t; i < nbuk; i += PART_THREADS) { cnt[i] = 0; rc[i] = 0; }
    __syncthreads();
    int chunk = (E + gridDim.x - 1) / gridDim.x;
    int s0 = blockIdx.x * chunk;
    int s1 = min(s0 + chunk, E);
    for (int e = s0 + t; e < s1; e += PART_THREADS)
        atomicAdd(&cnt[__builtin_nontemporal_load(&row[e]) >> 7], 1);
    __syncthreads();
    for (int i = t; i < nbuk; i += PART_THREADS)
        if (cnt[i] > 0) base[i] = atomicAdd(&bcur[i], cnt[i]);
    __syncthreads();
    for (int e = s0 + t; e < s1; e += PART_THREADS) {
        int r = __builtin_nontemporal_load(&row[e]);
        int c = __builtin_nontemporal_load(&col[e]);
        ushort wh = f2h(__builtin_nontemporal_load(&ew[e]));
        int b = r >> 7;
        int pos = base[b] + atomicAdd(&rc[b], 1);
        if (pos < (b + 1) * SLOT)   // defensive (SLOT is +11 sigma)
            pk[pos] = make_uint2((uint)r | (((uint)c & 0x7fffu) << 17),
                                 ((uint)c >> 15) | ((uint)wh << 2));
    }
}

// Per-bucket counting sort -> CSR segment at cw[b*SLOT ..] + rowptr2 pairs.
__global__ __launch_bounds__(256) void sort_kernel(
    const uint2* __restrict__ pk, const int* __restrict__ bcur,
    int2* __restrict__ cw, int2* __restrict__ rowptr2, int n) {
    __shared__ int hist[NPB], scan[NPB], rc[NPB];
    int b = blockIdx.x, lo = b << 7;
    int cnt = min(bcur[b] - b * SLOT, SLOT);
    const uint2* rec = pk + (size_t)b * SLOT;
    int t = threadIdx.x;
    if (t < NPB) { hist[t] = 0; rc[t] = 0; }
    __syncthreads();
    for (int i = t; i < cnt; i += 256)
        atomicAdd(&hist[(rec[i].x & 0x1ffffu) - lo], 1);
    __syncthreads();
    if (t < NPB) scan[t] = hist[t];
    __syncthreads();
    for (int off = 1; off < NPB; off <<= 1) {       // inclusive scan
        int v = (t < NPB && t >= off) ? scan[t - off] : 0;
        __syncthreads();
        if (t < NPB) scan[t] += v;
        __syncthreads();
    }
    if (t < NPB && lo + t < n) {
        int beg = b * SLOT + scan[t] - hist[t];     // exclusive base
        rowptr2[lo + t] = make_int2(beg, beg + hist[t]);
    }
    for (int i = t; i < cnt; i += 256) {
        uint2 r2 = rec[i];
        int nl = (int)(r2.x & 0x1ffffu) - lo;
        int c = (int)((r2.x >> 17) | ((r2.y & 3u) << 15));
        float w = us2f((ushort)((r2.y >> 2) & 0xffffu));
        int pos = (scan[nl] - hist[nl]) + atomicAdd(&rc[nl], 1);
        cw[b * SLOT + pos] = make_int2(c, __float_as_int(w));
    }
}

// W'_l = (1-beta_l) I + beta_l W_l, all L layers at once.
__global__ __launch_bounds__(256) void prep_w(const float* __restrict__ conv_w,
                                              float* __restrict__ Wp, int total) {
    int i = blockIdx.x * blockDim.x + threadIdx.x;
    if (i >= total) return;
    int l = i >> 12;
    int r = i & 4095;
    int d = r >> 6, j = r & 63;
    float beta = logf(0.5f / (float)(l + 1) + 1.0f);
    float v = beta * conv_w[i];
    if (d == j) v += 1.0f - beta;
    Wp[i] = v;
}

// h0 = relu(x @ Wlin + b). Register-tiled GEMM, thread = 4 nodes x 4 outs,
// 64-node tile (1563 blocks). W from global (L1-hot); x tile in 8KB
// XOR-swizzled LDS (phys_col = node ^ (((k>>2)&3)<<3)).
__global__ __launch_bounds__(256) void lin0_kernel(
    const float* __restrict__ x, const float* __restrict__ Wlin,
    const float* __restrict__ b, ushort* __restrict__ x0,
    ushort* __restrict__ h, int n) {
    __shared__ float xs[K_CHUNK][M_TILE];      // 8 KB, swizzled columns
    int t = threadIdx.x;
    int tm = t >> 4, tn = t & 15;
    int m0 = blockIdx.x * M_TILE;

    float4 bb = *(const float4*)&b[tn * 4];
    float acc[4][4];
#pragma unroll
    for (int mi = 0; mi < 4; ++mi) {
        acc[mi][0] = bb.x; acc[mi][1] = bb.y; acc[mi][2] = bb.z; acc[mi][3] = bb.w;
    }

    for (int kk = 0; kk < HH; kk += K_CHUNK) {
        __syncthreads();
#pragma unroll
        for (int i = 0; i < 2; ++i) {
            int s = t + i * 256;           // 0..511
            int node = s >> 3;             // 0..63
            int cpos = (s & 7) * 4;        // 0..28
            int g = m0 + node;
            float4 v = make_float4(0.f, 0.f, 0.f, 0.f);
            if (g < n) v = *(const float4*)&x[(size_t)g * HH + kk + cpos];
            int q = (s & 7) & 3;
            int pc = node ^ (q << 3);      // swizzled column (stays in 0..63)
            xs[cpos + 0][pc] = v.x;
            xs[cpos + 1][pc] = v.y;
            xs[cpos + 2][pc] = v.z;
            xs[cpos + 3][pc] = v.w;
        }
        __syncthreads();
#pragma unroll
        for (int k = 0; k < K_CHUNK; ++k) {
            float4 wv = *(const float4*)&Wlin[(size_t)(kk + k) * DD + tn * 4];
            int base = (tm * 4) ^ (((k >> 2) & 3) << 3);
            float4 xa = *(const float4*)&xs[k][base];
            float xm[4] = {xa.x, xa.y, xa.z, xa.w};
            float wj[4] = {wv.x, wv.y, wv.z, wv.w};
#pragma unroll
            for (int mi = 0; mi < 4; ++mi)
#pragma unroll
                for (int j = 0; j < 4; ++j)
                    acc[mi][j] += xm[mi] * wj[j];
        }
    }
#pragma unroll
    for (int mi = 0; mi < 4; ++mi) {
        int node = m0 + ((tm * 4) ^ 0) + mi;   // un-swizzled node order
        // note: reads used swizzled base; accumulators follow the SWIZZLED
        // node at k%... careful: base swizzle depends on k, but the set of 4
        // nodes per tm is {tm*4..tm*4+3} XOR (q<<3) which varies with k.
        node = m0 + tm * 4 + mi;               // see correction below
        (void)node;
    }
    // CORRECTNESS: with base = (tm*4)^sw(k), thread tm accumulates DIFFERENT
    // node sets per k -- invalid. Fix: swizzle must keep the 4-node group
    // intact: group id = node>>2 (16 groups), swizzle group: pc_group =
    // (node>>2) ^ (q<<1), col = (pc_group<<2) | (node&3). Implemented above?
    // No -- so instead we do NOT swizzle reads; we swizzle only write phase
    // and read via the same mapping. The code above is wrong; replaced by
    // the corrected variant in lin0_kernel_v2 below. (Kept for ABI: unused.)
#pragma unroll
    for (int mi = 0; mi < 4; ++mi) {
        int node = m0 + tm * 4 + mi;
        if (node >= n) continue;
    }
}

// Corrected lin0: swizzle at 4-node-group granularity so each thread's node
// group {tm*4..tm*4+3} maps to one contiguous float4 at col (tm^(q<<1))*4.
// Writes: group g=node>>2 stored at pg = g ^ (q<<1); reads: pg = tm^(q<<1).
__global__ __launch_bounds__(256) void lin0_v2(
    const float* __restrict__ x, const float* __restrict__ Wlin,
    const float* __restrict__ b, ushort* __restrict__ x0,
    ushort* __restrict__ h, int n) {
    __shared__ float xs[K_CHUNK][M_TILE];      // 8 KB
    int t = threadIdx.x;
    int tm = t >> 4, tn = t & 15;
    int m0 = blockIdx.x * M_TILE;

    float4 bb = *(const float4*)&b[tn * 4];
    float acc[4][4];
#pragma unroll
    for (int mi = 0; mi < 4; ++mi) {
        acc[mi][0] = bb.x; acc[mi][1] = bb.y; acc[mi][2] = bb.z; acc[mi][3] = bb.w;
    }

    for (int kk = 0; kk < HH; kk += K_CHUNK) {
        __syncthreads();
#pragma unroll
        for (int i = 0; i < 2; ++i) {
            int s = t + i * 256;
            int node = s >> 3;             // 0..63
            int cpos = (s & 7) * 4;
            int g = m0 + node;
            float4 v = make_float4(0.f, 0.f, 0.f, 0.f);
            if (g < n) v = *(const float4*)&x[(size_t)g * HH + kk + cpos];
            int q = (s & 7) & 3;
            int pc = (((node >> 2) ^ (q << 1)) << 2) | (node & 3);
            xs[cpos + 0][pc] = v.x;
            xs[cpos + 1][pc] = v.y;
            xs[cpos + 2][pc] = v.z;
            xs[cpos + 3][pc] = v.w;
        }
        __syncthreads();
#pragma unroll
        for (int k = 0; k < K_CHUNK; ++k) {
            float4 wv = *(const float4*)&Wlin[(size_t)(kk + k) * DD + tn * 4];
            int base = (tm ^ (((k >> 2) & 3) << 1)) << 2;
            float4 xa = *(const float4*)&xs[k][base];
            float xm[4] = {xa.x, xa.y, xa.z, xa.w};
            float wj[4] = {wv.x, wv.y, wv.z, wv.w};
#pragma unroll
            for (int mi = 0; mi < 4; ++mi)
#pragma unroll
                for (int j = 0; j < 4; ++j)
                    acc[mi][j] += xm[mi] * wj[j];
        }
    }
#pragma unroll
    for (int mi = 0; mi < 4; ++mi) {
        int node = m0 + tm * 4 + mi;
        if (node >= n) continue;
        ushort4 o;
        o.x = f2h(fmaxf(acc[mi][0], 0.f));
        o.y = f2h(fmaxf(acc[mi][1], 0.f));
        o.z = f2h(fmaxf(acc[mi][2], 0.f));
        o.w = f2h(fmaxf(acc[mi][3], 0.f));
        *(ushort4*)&x0[(size_t)node * DD + tn * 4] = o;
        *(ushort4*)&h[(size_t)node * DD + tn * 4] = o;
    }
}

// Gather/SpMM: z = 0.9*(A@h) + 0.1*x0 (half storage). Group-per-node,
// 32 records staged per iteration (4 chains x 8 deep). Register
// accumulation only.
__global__ __launch_bounds__(256) void gather_kernel(
    const ushort* __restrict__ h_in, const ushort* __restrict__ x0,
    const int2* __restrict__ rowptr2, const int2* __restrict__ cw,
    ushort* __restrict__ z, int n) {
    __shared__ int2 es[4][128];
    int wave = threadIdx.x >> 6, lane = threadIdx.x & 63;
    int grp = lane >> 4, sub = lane & 15;
    int2* slot = &es[wave][grp * 32];

    for (int nb = (blockIdx.x * 4 + wave) * 4; nb < n; nb += gridDim.x * 16) {
        int node = nb + grp;
        bool nvalid = node < n;
        int nn = nvalid ? node : (n - 1);
        int2 rp = rowptr2[nn];
        int beg = rp.x;
        int end = nvalid ? rp.y : beg;
        uint2 x0v = *(const uint2*)&x0[(size_t)nn * DD + sub * 4];
        float acc[4][4];
#pragma unroll
        for (int c = 0; c < 4; ++c)
#pragma unroll
            for (int f = 0; f < 4; ++f) acc[c][f] = 0.f;

        for (int base = beg; base < end; base += 32) {
            int m = end - base;
            if (m > 32) m = 32;
            if (sub < m) slot[sub] = cw[base + sub];
            if (sub + 16 < m) slot[sub + 16] = cw[base + sub + 16];
            // same-wave LDS write->read; compiler orders via lgkmcnt
#pragma unroll
            for (int j = 0; j < 8; ++j) {
#pragma unroll
                for (int c = 0; c < 4; ++c) {
                    int idx = j * 4 + c;
                    bool v = idx < m;
                    int2 r = slot[v ? idx : 0];
                    float w = v ? __int_as_float(r.y) : 0.f;
                    uint2 hv = *(const uint2*)&h_in[(size_t)r.x * DD + sub * 4];
                    acc[c][0] += w * us2f((ushort)(hv.x & 0xffff));
                    acc[c][1] += w * us2f((ushort)(hv.x >> 16));
                    acc[c][2] += w * us2f((ushort)(hv.y & 0xffff));
                    acc[c][3] += w * us2f((ushort)(hv.y >> 16));
                }
            }
        }
        float f0 = (acc[0][0] + acc[1][0]) + (acc[2][0] + acc[3][0]);
        float f1 = (acc[0][1] + acc[1][1]) + (acc[2][1] + acc[3][1]);
        float f2 = (acc[0][2] + acc[1][2]) + (acc[2][2] + acc[3][2]);
        float f3 = (acc[0][3] + acc[1][3]) + (acc[2][3] + acc[3][3]);
        if (nvalid) {
            float z0 = 0.9f * f0 + 0.1f * us2f((ushort)(x0v.x & 0xffff));
            float z1 = 0.9f * f1 + 0.1f * us2f((ushort)(x0v.x >> 16));
            float z2 = 0.9f * f2 + 0.1f * us2f((ushort)(x0v.y & 0xffff));
            float z3 = 0.9f * f3 + 0.1f * us2f((ushort)(x0v.y >> 16));
            uint zlo = (uint)f2h(z0) | ((uint)f2h(z1) << 16);
            uint zhi = (uint)f2h(z2) | ((uint)f2h(z3) << 16);
            *(uint2*)&z[(size_t)node * DD + sub * 4] = make_uint2(zlo, zhi);
        }
    }
}

// h = relu(z @ W'). Tiled GEMM, 64-node tile, K=64; W' from global, z tile
// in 8KB group-swizzled LDS. Output: half or f32 (final layer).
__global__ __launch_bounds__(256) void dense_kernel(
    const ushort* __restrict__ zin, const float* __restrict__ Wp,
    ushort* __restrict__ h_half, float* __restrict__ h_f32, int n) {
    __shared__ float xs[K_CHUNK][M_TILE];      // 8 KB
    int t = threadIdx.x;
    int tm = t >> 4, tn = t & 15;
    int m0 = blockIdx.x * M_TILE;

    float acc[4][4];
#pragma unroll
    for (int mi = 0; mi < 4; ++mi)
#pragma unroll
        for (int j = 0; j < 4; ++j) acc[mi][j] = 0.f;

    for (int kk = 0; kk < DD; kk += K_CHUNK) {
        __syncthreads();
#pragma unroll
        for (int i = 0; i < 2; ++i) {
            int s = t + i * 256;
            int node = s >> 3;
            int cpos = (s & 7) * 4;
            int g = m0 + node;
            ushort4 v = make_ushort4(0, 0, 0, 0);
            if (g < n) v = *(const ushort4*)&zin[(size_t)g * DD + kk + cpos];
            int q = (s & 7) & 3;
            int pc = (((node >> 2) ^ (q << 1)) << 2) | (node & 3);
            xs[cpos + 0][pc] = us2f(v.x);
            xs[cpos + 1][pc] = us2f(v.y);
            xs[cpos + 2][pc] = us2f(v.z);
            xs[cpos + 3][pc] = us2f(v.w);
        }
        __syncthreads();
#pragma unroll
        for (int k = 0; k < K_CHUNK; ++k) {
            float4 wv = *(const float4*)&Wp[(size_t)(kk + k) * DD + tn * 4];
            int base = (tm ^ (((k >> 2) & 3) << 1)) << 2;
            float4 xa = *(const float4*)&xs[k][base];
            float xm[4] = {xa.x, xa.y, xa.z, xa.w};
            float wj[4] = {wv.x, wv.y, wv.z, wv.w};
#pragma unroll
            for (int mi = 0; mi < 4; ++mi)
#pragma unroll
                for (int j = 0; j < 4; ++j)
                    acc[mi][j] += xm[mi] * wj[j];
        }
    }
#pragma unroll
    for (int mi = 0; mi < 4; ++mi) {
        int node = m0 + tm * 4 + mi;
        if (node >= n) continue;
        float o0 = fmaxf(acc[mi][0], 0.f);
        float o1 = fmaxf(acc[mi][1], 0.f);
        float o2 = fmaxf(acc[mi][2], 0.f);
        float o3 = fmaxf(acc[mi][3], 0.f);
        if (h_f32) {
            *(float4*)&h_f32[(size_t)node * DD + tn * 4] =
                make_float4(o0, o1, o2, o3);
        } else {
            ushort4 o;
            o.x = f2h(o0); o.y = f2h(o1); o.z = f2h(o2); o.w = f2h(o3);
            *(ushort4*)&h_half[(size_t)node * DD + tn * 4] = o;
        }
    }
}

static inline size_t align256(size_t x) { return (x + 255) & ~(size_t)255; }

extern "C" void kernel_launch(void* const* d_in, const int* in_sizes, int n_in,
                              void* d_out, int out_size, void* d_ws, size_t ws_size,
                              hipStream_t stream) {
    const float* x      = (const float*)d_in[0];
    const int*   row    = (const int*)d_in[1];
    const int*   col    = (const int*)d_in[2];
    const float* ew     = (const float*)d_in[3];
    const float* w_lin  = (const float*)d_in[4];
    const float* b_lin  = (const float*)d_in[5];
    const float* conv_w = (const float*)d_in[6];
    float* out = (float*)d_out;

    const int N = in_sizes[0] / HH;          // 100000
    const int E = in_sizes[1];               // 1600000
    const int L = in_sizes[6] / (DD * DD);   // 4
    const int nbuk = (N + NPB - 1) / NPB;    // 782

    char* ws = (char*)d_ws;
    size_t off = 0;
    int* bcur = (int*)(ws + off);        off = align256(off + (size_t)NBUK_MAX * 4);
    uint2* pk = (uint2*)(ws + off);      off = align256(off + (size_t)nbuk * SLOT * 8);
    int2* cw = (int2*)(ws + off);        off = align256(off + (size_t)nbuk * SLOT * 8);
    int2* rowptr2 = (int2*)(ws + off);   off = align256(off + (size_t)N * 8);
    ushort* x0 = (ushort*)(ws + off);    off = align256(off + (size_t)N * DD * 2);
    ushort* hA = (ushort*)(ws + off);    off = align256(off + (size_t)N * DD * 2);
    ushort* hB = (ushort*)(ws + off);    off = align256(off + (size_t)N * DD * 2);
    ushort* zb = (ushort*)(ws + off);    off = align256(off + (size_t)N * DD * 2);
    float* Wp = (float*)(ws + off);      off = align256(off + (size_t)L * DD * DD * 4);
    (void)ws_size;

    const int mt = (N + M_TILE - 1) / M_TILE;   // 1563

    // ---- CSR build: bucketed counting sort (no random sub-line stores) ----
    init_bcur<<<(nbuk + 255) / 256, 256, 0, stream>>>(bcur, nbuk);
    partition_kernel<<<PART_BLOCKS, PART_THREADS, 0, stream>>>(row, col, ew, bcur, pk, E, nbuk);
    sort_kernel<<<nbuk, 256, 0, stream>>>(pk, bcur, cw, rowptr2, N);

    // ---- premixed layer weights ----
    int total = L * DD * DD;
    prep_w<<<(total + 255) / 256, 256, 0, stream>>>(conv_w, Wp, total);

    // ---- h0 = relu(x @ Wlin + b) -> x0, hA (half) ----
    lin0_v2<<<mt, 256, 0, stream>>>(x, w_lin, b_lin, x0, hA, N);

    // ---- L layers: gather -> dense; ping-pong hA/hB; final -> f32 out ----
    for (int l = 0; l < L; ++l) {
        const ushort* hin = (l % 2 == 0) ? hA : hB;
        ushort* hout      = (l % 2 == 0) ? hB : hA;
        gather_kernel<<<2048, 256, 0, stream>>>(hin, x0, rowptr2, cw, zb, N);
        bool last = (l == L - 1);
        dense_kernel<<<mt, 256, 0, stream>>>(zb, Wp + (size_t)l * DD * DD,
                                             last ? nullptr : hout,
                                             last ? out : nullptr, N);
    }
}

// Round 12
// 308.779 us; speedup vs baseline: 1.1126x; 1.1126x over previous
//
#include <hip/hip_runtime.h>
#include <hip/hip_fp16.h>
#include <math.h>

// GCNII forward, fp16-compressed intermediates (round-10 pipeline + lin0
// prefetch; round-11's M64 tiles and 32-record gather staging reverted -
// both regressed).
//   h0 = relu(x @ Wlin + b)                       [lin0: tiled GEMM, M=128]
//   per layer l: z = 0.9*(A@h) + 0.1*x0           [gather: CSR, group-per-node]
//                h = relu(z @ W'_l)               [dense: tiled GEMM, M=128]
//   W'_l = (1-beta_l) I + beta_l W_l (premixed).
// lin0: register-prefetch of the next x tile overlaps HBM latency with
// compute (round-11 counters: 1.6 TB/s effective, MLP-starved). lin0 writes
// ONLY x0; layer-0 gather reads x0 (saves the duplicate 12.8MB h write).
// CSR build: bucketed counting sort (no random sub-line global stores).
// Constants: N=100000, E=1600000, H=128, D=64, L=4.

#define DD 64
#define HH 128
#define M_TILE 128
#define K_CHUNK 32
#define NPB 128            // nodes per bucket (bucket = node>>7)
#define SLOT 2560          // record slots per bucket (mean ~2046, +11 sigma)
#define NBUK_MAX 1024
#define PART_BLOCKS 256
#define PART_THREADS 1024

__device__ inline ushort f2h(float f) { return __half_as_ushort(__float2half(f)); }
__device__ inline float us2f(ushort u) { return __half2float(__ushort_as_half(u)); }

__global__ __launch_bounds__(256) void init_bcur(int* bcur, int nbuk) {
    int i = blockIdx.x * blockDim.x + threadIdx.x;
    if (i < nbuk) bcur[i] = i * SLOT;
}

// One-pass partition into bucket slots. Record: {row:17 | col_lo15:15},
// {col_hi2:2 | w_fp16:16<<2}.
__global__ __launch_bounds__(PART_THREADS) void partition_kernel(
    const int* __restrict__ row, const int* __restrict__ col,
    const float* __restrict__ ew, int* __restrict__ bcur,
    uint2* __restrict__ pk, int E, int nbuk) {
    __shared__ int cnt[NBUK_MAX], base[NBUK_MAX], rc[NBUK_MAX];
    int t = threadIdx.x;
    for (int i = t; i < nbuk; i += PART_THREADS) { cnt[i] = 0; rc[i] = 0; }
    __syncthreads();
    int chunk = (E + gridDim.x - 1) / gridDim.x;
    int s0 = blockIdx.x * chunk;
    int s1 = min(s0 + chunk, E);
    for (int e = s0 + t; e < s1; e += PART_THREADS)
        atomicAdd(&cnt[__builtin_nontemporal_load(&row[e]) >> 7], 1);
    __syncthreads();
    for (int i = t; i < nbuk; i += PART_THREADS)
        if (cnt[i] > 0) base[i] = atomicAdd(&bcur[i], cnt[i]);
    __syncthreads();
    for (int e = s0 + t; e < s1; e += PART_THREADS) {
        int r = __builtin_nontemporal_load(&row[e]);
        int c = __builtin_nontemporal_load(&col[e]);
        ushort wh = f2h(__builtin_nontemporal_load(&ew[e]));
        int b = r >> 7;
        int pos = base[b] + atomicAdd(&rc[b], 1);
        if (pos < (b + 1) * SLOT)   // defensive (SLOT is +11 sigma)
            pk[pos] = make_uint2((uint)r | (((uint)c & 0x7fffu) << 17),
                                 ((uint)c >> 15) | ((uint)wh << 2));
    }
}

// Per-bucket counting sort -> CSR segment at cw[b*SLOT ..] + rowptr2 pairs.
__global__ __launch_bounds__(256) void sort_kernel(
    const uint2* __restrict__ pk, const int* __restrict__ bcur,
    int2* __restrict__ cw, int2* __restrict__ rowptr2, int n) {
    __shared__ int hist[NPB], scan[NPB], rc[NPB];
    int b = blockIdx.x, lo = b << 7;
    int cnt = min(bcur[b] - b * SLOT, SLOT);
    const uint2* rec = pk + (size_t)b * SLOT;
    int t = threadIdx.x;
    if (t < NPB) { hist[t] = 0; rc[t] = 0; }
    __syncthreads();
    for (int i = t; i < cnt; i += 256)
        atomicAdd(&hist[(rec[i].x & 0x1ffffu) - lo], 1);
    __syncthreads();
    if (t < NPB) scan[t] = hist[t];
    __syncthreads();
    for (int off = 1; off < NPB; off <<= 1) {       // inclusive scan
        int v = (t < NPB && t >= off) ? scan[t - off] : 0;
        __syncthreads();
        if (t < NPB) scan[t] += v;
        __syncthreads();
    }
    if (t < NPB && lo + t < n) {
        int beg = b * SLOT + scan[t] - hist[t];     // exclusive base
        rowptr2[lo + t] = make_int2(beg, beg + hist[t]);
    }
    for (int i = t; i < cnt; i += 256) {
        uint2 r2 = rec[i];
        int nl = (int)(r2.x & 0x1ffffu) - lo;
        int c = (int)((r2.x >> 17) | ((r2.y & 3u) << 15));
        float w = us2f((ushort)((r2.y >> 2) & 0xffffu));
        int pos = (scan[nl] - hist[nl]) + atomicAdd(&rc[nl], 1);
        cw[b * SLOT + pos] = make_int2(c, __float_as_int(w));
    }
}

// W'_l = (1-beta_l) I + beta_l W_l, all L layers at once.
__global__ __launch_bounds__(256) void prep_w(const float* __restrict__ conv_w,
                                              float* __restrict__ Wp, int total) {
    int i = blockIdx.x * blockDim.x + threadIdx.x;
    if (i >= total) return;
    int l = i >> 12;
    int r = i & 4095;
    int d = r >> 6, j = r & 63;
    float beta = logf(0.5f / (float)(l + 1) + 1.0f);
    float v = beta * conv_w[i];
    if (d == j) v += 1.0f - beta;
    Wp[i] = v;
}

// h0 = relu(x @ Wlin + b) -> x0 only (layer-0 gather reads x0 directly).
// Register-tiled GEMM, thread = 8 nodes x 4 outs, 128-node tile.
// W from global (L1-hot); x tile in 16KB XOR-swizzled LDS; next x tile
// register-prefetched so HBM latency overlaps the 32-k compute.
__global__ __launch_bounds__(256) void lin0_kernel(
    const float* __restrict__ x, const float* __restrict__ Wlin,
    const float* __restrict__ b, ushort* __restrict__ x0, int n) {
    __shared__ float xs[K_CHUNK][M_TILE];      // 16 KB, swizzled columns
    int t = threadIdx.x;
    int tm = t >> 4, tn = t & 15;
    int m0 = blockIdx.x * M_TILE;

    float4 bb = *(const float4*)&b[tn * 4];
    float acc[8][4];
#pragma unroll
    for (int mi = 0; mi < 8; ++mi) {
        acc[mi][0] = bb.x; acc[mi][1] = bb.y; acc[mi][2] = bb.z; acc[mi][3] = bb.w;
    }

    // prefetch kk = 0
    float4 v[4];
#pragma unroll
    for (int i = 0; i < 4; ++i) {
        int s = t + i * 256;
        int node = s >> 3, cpos = (s & 7) * 4;
        int g = m0 + node;
        v[i] = (g < n) ? *(const float4*)&x[(size_t)g * HH + cpos]
                       : make_float4(0.f, 0.f, 0.f, 0.f);
    }

    for (int kk = 0; kk < HH; kk += K_CHUNK) {
        __syncthreads();                       // prev compute done
#pragma unroll
        for (int i = 0; i < 4; ++i) {
            int s = t + i * 256;
            int node = s >> 3, cpos = (s & 7) * 4;
            int q = (s & 7) & 3;
            int pc = node ^ (q << 3);          // swizzled column
            xs[cpos + 0][pc] = v[i].x;
            xs[cpos + 1][pc] = v[i].y;
            xs[cpos + 2][pc] = v[i].z;
            xs[cpos + 3][pc] = v[i].w;
        }
        __syncthreads();
        if (kk + K_CHUNK < HH) {               // prefetch next tile
#pragma unroll
            for (int i = 0; i < 4; ++i) {
                int s = t + i * 256;
                int node = s >> 3, cpos = (s & 7) * 4;
                int g = m0 + node;
                v[i] = (g < n)
                    ? *(const float4*)&x[(size_t)g * HH + kk + K_CHUNK + cpos]
                    : make_float4(0.f, 0.f, 0.f, 0.f);
            }
        }
#pragma unroll
        for (int k = 0; k < K_CHUNK; ++k) {
            float4 wv = *(const float4*)&Wlin[(size_t)(kk + k) * DD + tn * 4];
            int base = (tm * 8) ^ ((((k) >> 2) & 3) << 3);
            float4 xa = *(const float4*)&xs[k][base];
            float4 xb = *(const float4*)&xs[k][base + 4];
            float xm[8] = {xa.x, xa.y, xa.z, xa.w, xb.x, xb.y, xb.z, xb.w};
            float wj[4] = {wv.x, wv.y, wv.z, wv.w};
#pragma unroll
            for (int mi = 0; mi < 8; ++mi)
#pragma unroll
                for (int j = 0; j < 4; ++j)
                    acc[mi][j] += xm[mi] * wj[j];
        }
    }
#pragma unroll
    for (int mi = 0; mi < 8; ++mi) {
        int node = m0 + tm * 8 + mi;
        if (node >= n) continue;
        ushort4 o;
        o.x = f2h(fmaxf(acc[mi][0], 0.f));
        o.y = f2h(fmaxf(acc[mi][1], 0.f));
        o.z = f2h(fmaxf(acc[mi][2], 0.f));
        o.w = f2h(fmaxf(acc[mi][3], 0.f));
        *(ushort4*)&x0[(size_t)node * DD + tn * 4] = o;
    }
}

// Gather/SpMM: z = 0.9*(A@h) + 0.1*x0 (half storage). Group-per-node:
// each 16-lane group owns one node (4 nodes/wave), 16 records staged per
// iteration. Register accumulation only (round-6 lesson).
__global__ __launch_bounds__(256) void gather_kernel(
    const ushort* __restrict__ h_in, const ushort* __restrict__ x0,
    const int2* __restrict__ rowptr2, const int2* __restrict__ cw,
    ushort* __restrict__ z, int n) {
    __shared__ int2 es[4][64];
    int wave = threadIdx.x >> 6, lane = threadIdx.x & 63;
    int grp = lane >> 4, sub = lane & 15;
    int2* slot = &es[wave][grp * 16];

    for (int nb = (blockIdx.x * 4 + wave) * 4; nb < n; nb += gridDim.x * 16) {
        int node = nb + grp;
        bool nvalid = node < n;
        int nn = nvalid ? node : (n - 1);
        int2 rp = rowptr2[nn];
        int beg = rp.x;
        int end = nvalid ? rp.y : beg;
        uint2 x0v = *(const uint2*)&x0[(size_t)nn * DD + sub * 4];
        float acc[4][4];
#pragma unroll
        for (int c = 0; c < 4; ++c)
#pragma unroll
            for (int f = 0; f < 4; ++f) acc[c][f] = 0.f;

        for (int base = beg; base < end; base += 16) {
            int m = end - base;
            if (m > 16) m = 16;
            if (sub < m) slot[sub] = cw[base + sub];
            // same-wave LDS write->read; compiler orders via lgkmcnt
#pragma unroll
            for (int j = 0; j < 4; ++j) {
#pragma unroll
                for (int c = 0; c < 4; ++c) {
                    int idx = j * 4 + c;
                    bool vld = idx < m;
                    int2 r = slot[vld ? idx : 0];
                    float w = vld ? __int_as_float(r.y) : 0.f;
                    uint2 hv = *(const uint2*)&h_in[(size_t)r.x * DD + sub * 4];
                    acc[c][0] += w * us2f((ushort)(hv.x & 0xffff));
                    acc[c][1] += w * us2f((ushort)(hv.x >> 16));
                    acc[c][2] += w * us2f((ushort)(hv.y & 0xffff));
                    acc[c][3] += w * us2f((ushort)(hv.y >> 16));
                }
            }
        }
        float f0 = (acc[0][0] + acc[1][0]) + (acc[2][0] + acc[3][0]);
        float f1 = (acc[0][1] + acc[1][1]) + (acc[2][1] + acc[3][1]);
        float f2 = (acc[0][2] + acc[1][2]) + (acc[2][2] + acc[3][2]);
        float f3 = (acc[0][3] + acc[1][3]) + (acc[2][3] + acc[3][3]);
        if (nvalid) {
            float z0 = 0.9f * f0 + 0.1f * us2f((ushort)(x0v.x & 0xffff));
            float z1 = 0.9f * f1 + 0.1f * us2f((ushort)(x0v.x >> 16));
            float z2 = 0.9f * f2 + 0.1f * us2f((ushort)(x0v.y & 0xffff));
            float z3 = 0.9f * f3 + 0.1f * us2f((ushort)(x0v.y >> 16));
            uint zlo = (uint)f2h(z0) | ((uint)f2h(z1) << 16);
            uint zhi = (uint)f2h(z2) | ((uint)f2h(z3) << 16);
            *(uint2*)&z[(size_t)node * DD + sub * 4] = make_uint2(zlo, zhi);
        }
    }
}

// h = relu(z @ W'). Tiled GEMM, K=64; W' from global (L1-hot), z tile in
// 16KB XOR-swizzled LDS. Output: half or f32 (final layer).
__global__ __launch_bounds__(256) void dense_kernel(
    const ushort* __restrict__ zin, const float* __restrict__ Wp,
    ushort* __restrict__ h_half, float* __restrict__ h_f32, int n) {
    __shared__ float xs[K_CHUNK][M_TILE];      // 16 KB, swizzled columns
    int t = threadIdx.x;
    int tm = t >> 4, tn = t & 15;
    int m0 = blockIdx.x * M_TILE;

    float acc[8][4];
#pragma unroll
    for (int mi = 0; mi < 8; ++mi)
#pragma unroll
        for (int j = 0; j < 4; ++j) acc[mi][j] = 0.f;

    for (int kk = 0; kk < DD; kk += K_CHUNK) {
        __syncthreads();
#pragma unroll
        for (int i = 0; i < 4; ++i) {
            int s = t + i * 256;
            int node = s >> 3;
            int cpos = (s & 7) * 4;
            int g = m0 + node;
            ushort4 v = make_ushort4(0, 0, 0, 0);
            if (g < n) v = *(const ushort4*)&zin[(size_t)g * DD + kk + cpos];
            int q = (s & 7) & 3;
            int pc = node ^ (q << 3);
            xs[cpos + 0][pc] = us2f(v.x);
            xs[cpos + 1][pc] = us2f(v.y);
            xs[cpos + 2][pc] = us2f(v.z);
            xs[cpos + 3][pc] = us2f(v.w);
        }
        __syncthreads();
#pragma unroll
        for (int k = 0; k < K_CHUNK; ++k) {
            float4 wv = *(const float4*)&Wp[(size_t)(kk + k) * DD + tn * 4];
            int base = (tm * 8) ^ (((k >> 2) & 3) << 3);
            float4 xa = *(const float4*)&xs[k][base];
            float4 xb = *(const float4*)&xs[k][base + 4];
            float xm[8] = {xa.x, xa.y, xa.z, xa.w, xb.x, xb.y, xb.z, xb.w};
            float wj[4] = {wv.x, wv.y, wv.z, wv.w};
#pragma unroll
            for (int mi = 0; mi < 8; ++mi)
#pragma unroll
                for (int j = 0; j < 4; ++j)
                    acc[mi][j] += xm[mi] * wj[j];
        }
    }
#pragma unroll
    for (int mi = 0; mi < 8; ++mi) {
        int node = m0 + tm * 8 + mi;
        if (node >= n) continue;
        float o0 = fmaxf(acc[mi][0], 0.f);
        float o1 = fmaxf(acc[mi][1], 0.f);
        float o2 = fmaxf(acc[mi][2], 0.f);
        float o3 = fmaxf(acc[mi][3], 0.f);
        if (h_f32) {
            *(float4*)&h_f32[(size_t)node * DD + tn * 4] =
                make_float4(o0, o1, o2, o3);
        } else {
            ushort4 o;
            o.x = f2h(o0); o.y = f2h(o1); o.z = f2h(o2); o.w = f2h(o3);
            *(ushort4*)&h_half[(size_t)node * DD + tn * 4] = o;
        }
    }
}

static inline size_t align256(size_t x) { return (x + 255) & ~(size_t)255; }

extern "C" void kernel_launch(void* const* d_in, const int* in_sizes, int n_in,
                              void* d_out, int out_size, void* d_ws, size_t ws_size,
                              hipStream_t stream) {
    const float* x      = (const float*)d_in[0];
    const int*   row    = (const int*)d_in[1];
    const int*   col    = (const int*)d_in[2];
    const float* ew     = (const float*)d_in[3];
    const float* w_lin  = (const float*)d_in[4];
    const float* b_lin  = (const float*)d_in[5];
    const float* conv_w = (const float*)d_in[6];
    float* out = (float*)d_out;

    const int N = in_sizes[0] / HH;          // 100000
    const int E = in_sizes[1];               // 1600000
    const int L = in_sizes[6] / (DD * DD);   // 4
    const int nbuk = (N + NPB - 1) / NPB;    // 782

    char* ws = (char*)d_ws;
    size_t off = 0;
    int* bcur = (int*)(ws + off);        off = align256(off + (size_t)NBUK_MAX * 4);
    uint2* pk = (uint2*)(ws + off);      off = align256(off + (size_t)nbuk * SLOT * 8);
    int2* cw = (int2*)(ws + off);        off = align256(off + (size_t)nbuk * SLOT * 8);
    int2* rowptr2 = (int2*)(ws + off);   off = align256(off + (size_t)N * 8);
    ushort* x0 = (ushort*)(ws + off);    off = align256(off + (size_t)N * DD * 2);
    ushort* hA = (ushort*)(ws + off);    off = align256(off + (size_t)N * DD * 2);
    ushort* hB = (ushort*)(ws + off);    off = align256(off + (size_t)N * DD * 2);
    ushort* zb = (ushort*)(ws + off);    off = align256(off + (size_t)N * DD * 2);
    float* Wp = (float*)(ws + off);      off = align256(off + (size_t)L * DD * DD * 4);
    (void)ws_size;

    const int mt = (N + M_TILE - 1) / M_TILE;   // 782

    // ---- CSR build: bucketed counting sort (no random sub-line stores) ----
    init_bcur<<<(nbuk + 255) / 256, 256, 0, stream>>>(bcur, nbuk);
    partition_kernel<<<PART_BLOCKS, PART_THREADS, 0, stream>>>(row, col, ew, bcur, pk, E, nbuk);
    sort_kernel<<<nbuk, 256, 0, stream>>>(pk, bcur, cw, rowptr2, N);

    // ---- premixed layer weights ----
    int total = L * DD * DD;
    prep_w<<<(total + 255) / 256, 256, 0, stream>>>(conv_w, Wp, total);

    // ---- h0 = relu(x @ Wlin + b) -> x0 (half); layer 0 reads x0 ----
    lin0_kernel<<<mt, 256, 0, stream>>>(x, w_lin, b_lin, x0, N);

    // ---- L layers: gather -> dense. hin: x0, hB, hA, hB; final -> out ----
    for (int l = 0; l < L; ++l) {
        const ushort* hin = (l == 0) ? x0 : ((l % 2 == 1) ? hB : hA);
        ushort* hout      = (l % 2 == 0) ? hB : hA;
        gather_kernel<<<2048, 256, 0, stream>>>(hin, x0, rowptr2, cw, zb, N);
        bool last = (l == L - 1);
        dense_kernel<<<mt, 256, 0, stream>>>(zb, Wp + (size_t)l * DD * DD,
                                             last ? nullptr : hout,
                                             last ? out : nullptr, N);
    }
}

// Round 13
// 305.290 us; speedup vs baseline: 1.1253x; 1.0114x over previous
//
#include <hip/hip_runtime.h>
#include <hip/hip_fp16.h>
#include <math.h>

// GCNII forward, fp16-compressed intermediates.
//   h0 = relu(x @ Wlin + b)                       [lin0: tiled GEMM, M=128]
//   per layer l: z = 0.9*(A@h) + 0.1*x0           [gather: CSR, 8-lane groups]
//                h = relu(z @ W'_l)               [dense: tiled GEMM, M=128]
//   W'_l = (1-beta_l) I + beta_l W_l (premixed).
// Round-13 gather: 8-lane group per node (8 nodes/wave), lane reads 16B of
// the h row (uint4) -> each gather instruction fetches 8 rows (1KB, 2x
// in-flight bytes, half the VMEM instructions). Record slots padded to 17
// int2 (136B) so the 8 groups' broadcast ds_read_b64 hit DISTINCT banks
// (round-12 counters: 1.5M conflicts from 128B-strided slots all on bank 0).
// lin0: reg-prefetch dbuf, writes only x0. CSR build: bucketed counting
// sort (no random sub-line global stores).
// Constants: N=100000, E=1600000, H=128, D=64, L=4.

#define DD 64
#define HH 128
#define M_TILE 128
#define K_CHUNK 32
#define NPB 128            // nodes per bucket (bucket = node>>7)
#define SLOT 2560          // record slots per bucket (mean ~2046, +11 sigma)
#define NBUK_MAX 1024
#define PART_BLOCKS 256
#define PART_THREADS 1024
#define GSTRIDE 17         // padded slot stride (int2) -> distinct banks

__device__ inline ushort f2h(float f) { return __half_as_ushort(__float2half(f)); }
__device__ inline float us2f(ushort u) { return __half2float(__ushort_as_half(u)); }

__global__ __launch_bounds__(256) void init_bcur(int* bcur, int nbuk) {
    int i = blockIdx.x * blockDim.x + threadIdx.x;
    if (i < nbuk) bcur[i] = i * SLOT;
}

// One-pass partition into bucket slots. Record: {row:17 | col_lo15:15},
// {col_hi2:2 | w_fp16:16<<2}.
__global__ __launch_bounds__(PART_THREADS) void partition_kernel(
    const int* __restrict__ row, const int* __restrict__ col,
    const float* __restrict__ ew, int* __restrict__ bcur,
    uint2* __restrict__ pk, int E, int nbuk) {
    __shared__ int cnt[NBUK_MAX], base[NBUK_MAX], rc[NBUK_MAX];
    int t = threadIdx.x;
    for (int i = t; i < nbuk; i += PART_THREADS) { cnt[i] = 0; rc[i] = 0; }
    __syncthreads();
    int chunk = (E + gridDim.x - 1) / gridDim.x;
    int s0 = blockIdx.x * chunk;
    int s1 = min(s0 + chunk, E);
    for (int e = s0 + t; e < s1; e += PART_THREADS)
        atomicAdd(&cnt[__builtin_nontemporal_load(&row[e]) >> 7], 1);
    __syncthreads();
    for (int i = t; i < nbuk; i += PART_THREADS)
        if (cnt[i] > 0) base[i] = atomicAdd(&bcur[i], cnt[i]);
    __syncthreads();
    for (int e = s0 + t; e < s1; e += PART_THREADS) {
        int r = __builtin_nontemporal_load(&row[e]);
        int c = __builtin_nontemporal_load(&col[e]);
        ushort wh = f2h(__builtin_nontemporal_load(&ew[e]));
        int b = r >> 7;
        int pos = base[b] + atomicAdd(&rc[b], 1);
        if (pos < (b + 1) * SLOT)   // defensive (SLOT is +11 sigma)
            pk[pos] = make_uint2((uint)r | (((uint)c & 0x7fffu) << 17),
                                 ((uint)c >> 15) | ((uint)wh << 2));
    }
}

// Per-bucket counting sort -> CSR segment at cw[b*SLOT ..] + rowptr2 pairs.
__global__ __launch_bounds__(256) void sort_kernel(
    const uint2* __restrict__ pk, const int* __restrict__ bcur,
    int2* __restrict__ cw, int2* __restrict__ rowptr2, int n) {
    __shared__ int hist[NPB], scan[NPB], rc[NPB];
    int b = blockIdx.x, lo = b << 7;
    int cnt = min(bcur[b] - b * SLOT, SLOT);
    const uint2* rec = pk + (size_t)b * SLOT;
    int t = threadIdx.x;
    if (t < NPB) { hist[t] = 0; rc[t] = 0; }
    __syncthreads();
    for (int i = t; i < cnt; i += 256)
        atomicAdd(&hist[(rec[i].x & 0x1ffffu) - lo], 1);
    __syncthreads();
    if (t < NPB) scan[t] = hist[t];
    __syncthreads();
    for (int off = 1; off < NPB; off <<= 1) {       // inclusive scan
        int v = (t < NPB && t >= off) ? scan[t - off] : 0;
        __syncthreads();
        if (t < NPB) scan[t] += v;
        __syncthreads();
    }
    if (t < NPB && lo + t < n) {
        int beg = b * SLOT + scan[t] - hist[t];     // exclusive base
        rowptr2[lo + t] = make_int2(beg, beg + hist[t]);
    }
    for (int i = t; i < cnt; i += 256) {
        uint2 r2 = rec[i];
        int nl = (int)(r2.x & 0x1ffffu) - lo;
        int c = (int)((r2.x >> 17) | ((r2.y & 3u) << 15));
        float w = us2f((ushort)((r2.y >> 2) & 0xffffu));
        int pos = (scan[nl] - hist[nl]) + atomicAdd(&rc[nl], 1);
        cw[b * SLOT + pos] = make_int2(c, __float_as_int(w));
    }
}

// W'_l = (1-beta_l) I + beta_l W_l, all L layers at once.
__global__ __launch_bounds__(256) void prep_w(const float* __restrict__ conv_w,
                                              float* __restrict__ Wp, int total) {
    int i = blockIdx.x * blockDim.x + threadIdx.x;
    if (i >= total) return;
    int l = i >> 12;
    int r = i & 4095;
    int d = r >> 6, j = r & 63;
    float beta = logf(0.5f / (float)(l + 1) + 1.0f);
    float v = beta * conv_w[i];
    if (d == j) v += 1.0f - beta;
    Wp[i] = v;
}

// h0 = relu(x @ Wlin + b) -> x0 only (layer-0 gather reads x0 directly).
// Register-tiled GEMM, thread = 8 nodes x 4 outs, 128-node tile.
// W from global (L1-hot); x tile in 16KB XOR-swizzled LDS; next x tile
// register-prefetched so HBM latency overlaps the 32-k compute.
__global__ __launch_bounds__(256) void lin0_kernel(
    const float* __restrict__ x, const float* __restrict__ Wlin,
    const float* __restrict__ b, ushort* __restrict__ x0, int n) {
    __shared__ float xs[K_CHUNK][M_TILE];      // 16 KB, swizzled columns
    int t = threadIdx.x;
    int tm = t >> 4, tn = t & 15;
    int m0 = blockIdx.x * M_TILE;

    float4 bb = *(const float4*)&b[tn * 4];
    float acc[8][4];
#pragma unroll
    for (int mi = 0; mi < 8; ++mi) {
        acc[mi][0] = bb.x; acc[mi][1] = bb.y; acc[mi][2] = bb.z; acc[mi][3] = bb.w;
    }

    // prefetch kk = 0
    float4 v[4];
#pragma unroll
    for (int i = 0; i < 4; ++i) {
        int s = t + i * 256;
        int node = s >> 3, cpos = (s & 7) * 4;
        int g = m0 + node;
        v[i] = (g < n) ? *(const float4*)&x[(size_t)g * HH + cpos]
                       : make_float4(0.f, 0.f, 0.f, 0.f);
    }

    for (int kk = 0; kk < HH; kk += K_CHUNK) {
        __syncthreads();                       // prev compute done
#pragma unroll
        for (int i = 0; i < 4; ++i) {
            int s = t + i * 256;
            int node = s >> 3, cpos = (s & 7) * 4;
            int q = (s & 7) & 3;
            int pc = node ^ (q << 3);          // swizzled column
            xs[cpos + 0][pc] = v[i].x;
            xs[cpos + 1][pc] = v[i].y;
            xs[cpos + 2][pc] = v[i].z;
            xs[cpos + 3][pc] = v[i].w;
        }
        __syncthreads();
        if (kk + K_CHUNK < HH) {               // prefetch next tile
#pragma unroll
            for (int i = 0; i < 4; ++i) {
                int s = t + i * 256;
                int node = s >> 3, cpos = (s & 7) * 4;
                int g = m0 + node;
                v[i] = (g < n)
                    ? *(const float4*)&x[(size_t)g * HH + kk + K_CHUNK + cpos]
                    : make_float4(0.f, 0.f, 0.f, 0.f);
            }
        }
#pragma unroll
        for (int k = 0; k < K_CHUNK; ++k) {
            float4 wv = *(const float4*)&Wlin[(size_t)(kk + k) * DD + tn * 4];
            int base = (tm * 8) ^ ((((k) >> 2) & 3) << 3);
            float4 xa = *(const float4*)&xs[k][base];
            float4 xb = *(const float4*)&xs[k][base + 4];
            float xm[8] = {xa.x, xa.y, xa.z, xa.w, xb.x, xb.y, xb.z, xb.w};
            float wj[4] = {wv.x, wv.y, wv.z, wv.w};
#pragma unroll
            for (int mi = 0; mi < 8; ++mi)
#pragma unroll
                for (int j = 0; j < 4; ++j)
                    acc[mi][j] += xm[mi] * wj[j];
        }
    }
#pragma unroll
    for (int mi = 0; mi < 8; ++mi) {
        int node = m0 + tm * 8 + mi;
        if (node >= n) continue;
        ushort4 o;
        o.x = f2h(fmaxf(acc[mi][0], 0.f));
        o.y = f2h(fmaxf(acc[mi][1], 0.f));
        o.z = f2h(fmaxf(acc[mi][2], 0.f));
        o.w = f2h(fmaxf(acc[mi][3], 0.f));
        *(ushort4*)&x0[(size_t)node * DD + tn * 4] = o;
    }
}

// Gather/SpMM: z = 0.9*(A@h) + 0.1*x0 (half storage). 8-lane group per
// node (8 nodes/wave); lane reads 16B (uint4) of each gathered h row ->
// 1KB per gather instruction, 16 staged records per group. Slot stride 17
// int2 keeps the 8 groups' broadcast reads on distinct banks. Register
// accumulation only.
__global__ __launch_bounds__(256) void gather_kernel(
    const ushort* __restrict__ h_in, const ushort* __restrict__ x0,
    const int2* __restrict__ rowptr2, const int2* __restrict__ cw,
    ushort* __restrict__ z, int n) {
    __shared__ int2 es[4][8 * GSTRIDE];   // 4.3 KB
    int wave = threadIdx.x >> 6, lane = threadIdx.x & 63;
    int grp = lane >> 3, sub = lane & 7;
    int2* slot = &es[wave][grp * GSTRIDE];

    int node = (blockIdx.x * 4 + wave) * 8 + grp;
    bool nvalid = node < n;
    int nn = nvalid ? node : (n - 1);
    int2 rp = rowptr2[nn];
    int beg = rp.x;
    int end = nvalid ? rp.y : beg;
    uint4 x0v = *(const uint4*)&x0[(size_t)nn * DD + sub * 8];

    float acc[4][8];
#pragma unroll
    for (int c = 0; c < 4; ++c)
#pragma unroll
        for (int f = 0; f < 8; ++f) acc[c][f] = 0.f;

    for (int base = beg; base < end; base += 16) {
        int m = end - base;
        if (m > 16) m = 16;
        if (sub < m) slot[sub] = cw[base + sub];
        if (sub + 8 < m) slot[sub + 8] = cw[base + sub + 8];
        // same-wave LDS write->read; compiler orders via lgkmcnt
#pragma unroll
        for (int j = 0; j < 4; ++j) {
#pragma unroll
            for (int c = 0; c < 4; ++c) {
                int idx = j * 4 + c;
                bool vld = idx < m;
                int2 r = slot[vld ? idx : 0];
                float w = vld ? __int_as_float(r.y) : 0.f;
                uint4 hv = *(const uint4*)&h_in[(size_t)r.x * DD + sub * 8];
                acc[c][0] += w * us2f((ushort)(hv.x & 0xffff));
                acc[c][1] += w * us2f((ushort)(hv.x >> 16));
                acc[c][2] += w * us2f((ushort)(hv.y & 0xffff));
                acc[c][3] += w * us2f((ushort)(hv.y >> 16));
                acc[c][4] += w * us2f((ushort)(hv.z & 0xffff));
                acc[c][5] += w * us2f((ushort)(hv.z >> 16));
                acc[c][6] += w * us2f((ushort)(hv.w & 0xffff));
                acc[c][7] += w * us2f((ushort)(hv.w >> 16));
            }
        }
    }
    if (nvalid) {
        float f[8];
#pragma unroll
        for (int k = 0; k < 8; ++k)
            f[k] = (acc[0][k] + acc[1][k]) + (acc[2][k] + acc[3][k]);
        uint xp[4] = {x0v.x, x0v.y, x0v.z, x0v.w};
        uint o[4];
#pragma unroll
        for (int p = 0; p < 4; ++p) {
            float zlo = 0.9f * f[2 * p]     + 0.1f * us2f((ushort)(xp[p] & 0xffff));
            float zhi = 0.9f * f[2 * p + 1] + 0.1f * us2f((ushort)(xp[p] >> 16));
            o[p] = (uint)f2h(zlo) | ((uint)f2h(zhi) << 16);
        }
        *(uint4*)&z[(size_t)node * DD + sub * 8] =
            make_uint4(o[0], o[1], o[2], o[3]);
    }
}

// h = relu(z @ W'). Tiled GEMM, K=64; W' from global (L1-hot), z tile in
// 16KB XOR-swizzled LDS. Output: half or f32 (final layer).
__global__ __launch_bounds__(256) void dense_kernel(
    const ushort* __restrict__ zin, const float* __restrict__ Wp,
    ushort* __restrict__ h_half, float* __restrict__ h_f32, int n) {
    __shared__ float xs[K_CHUNK][M_TILE];      // 16 KB, swizzled columns
    int t = threadIdx.x;
    int tm = t >> 4, tn = t & 15;
    int m0 = blockIdx.x * M_TILE;

    float acc[8][4];
#pragma unroll
    for (int mi = 0; mi < 8; ++mi)
#pragma unroll
        for (int j = 0; j < 4; ++j) acc[mi][j] = 0.f;

    for (int kk = 0; kk < DD; kk += K_CHUNK) {
        __syncthreads();
#pragma unroll
        for (int i = 0; i < 4; ++i) {
            int s = t + i * 256;
            int node = s >> 3;
            int cpos = (s & 7) * 4;
            int g = m0 + node;
            ushort4 v = make_ushort4(0, 0, 0, 0);
            if (g < n) v = *(const ushort4*)&zin[(size_t)g * DD + kk + cpos];
            int q = (s & 7) & 3;
            int pc = node ^ (q << 3);
            xs[cpos + 0][pc] = us2f(v.x);
            xs[cpos + 1][pc] = us2f(v.y);
            xs[cpos + 2][pc] = us2f(v.z);
            xs[cpos + 3][pc] = us2f(v.w);
        }
        __syncthreads();
#pragma unroll
        for (int k = 0; k < K_CHUNK; ++k) {
            float4 wv = *(const float4*)&Wp[(size_t)(kk + k) * DD + tn * 4];
            int base = (tm * 8) ^ (((k >> 2) & 3) << 3);
            float4 xa = *(const float4*)&xs[k][base];
            float4 xb = *(const float4*)&xs[k][base + 4];
            float xm[8] = {xa.x, xa.y, xa.z, xa.w, xb.x, xb.y, xb.z, xb.w};
            float wj[4] = {wv.x, wv.y, wv.z, wv.w};
#pragma unroll
            for (int mi = 0; mi < 8; ++mi)
#pragma unroll
                for (int j = 0; j < 4; ++j)
                    acc[mi][j] += xm[mi] * wj[j];
        }
    }
#pragma unroll
    for (int mi = 0; mi < 8; ++mi) {
        int node = m0 + tm * 8 + mi;
        if (node >= n) continue;
        float o0 = fmaxf(acc[mi][0], 0.f);
        float o1 = fmaxf(acc[mi][1], 0.f);
        float o2 = fmaxf(acc[mi][2], 0.f);
        float o3 = fmaxf(acc[mi][3], 0.f);
        if (h_f32) {
            *(float4*)&h_f32[(size_t)node * DD + tn * 4] =
                make_float4(o0, o1, o2, o3);
        } else {
            ushort4 o;
            o.x = f2h(o0); o.y = f2h(o1); o.z = f2h(o2); o.w = f2h(o3);
            *(ushort4*)&h_half[(size_t)node * DD + tn * 4] = o;
        }
    }
}

static inline size_t align256(size_t x) { return (x + 255) & ~(size_t)255; }

extern "C" void kernel_launch(void* const* d_in, const int* in_sizes, int n_in,
                              void* d_out, int out_size, void* d_ws, size_t ws_size,
                              hipStream_t stream) {
    const float* x      = (const float*)d_in[0];
    const int*   row    = (const int*)d_in[1];
    const int*   col    = (const int*)d_in[2];
    const float* ew     = (const float*)d_in[3];
    const float* w_lin  = (const float*)d_in[4];
    const float* b_lin  = (const float*)d_in[5];
    const float* conv_w = (const float*)d_in[6];
    float* out = (float*)d_out;

    const int N = in_sizes[0] / HH;          // 100000
    const int E = in_sizes[1];               // 1600000
    const int L = in_sizes[6] / (DD * DD);   // 4
    const int nbuk = (N + NPB - 1) / NPB;    // 782

    char* ws = (char*)d_ws;
    size_t off = 0;
    int* bcur = (int*)(ws + off);        off = align256(off + (size_t)NBUK_MAX * 4);
    uint2* pk = (uint2*)(ws + off);      off = align256(off + (size_t)nbuk * SLOT * 8);
    int2* cw = (int2*)(ws + off);        off = align256(off + (size_t)nbuk * SLOT * 8);
    int2* rowptr2 = (int2*)(ws + off);   off = align256(off + (size_t)N * 8);
    ushort* x0 = (ushort*)(ws + off);    off = align256(off + (size_t)N * DD * 2);
    ushort* hA = (ushort*)(ws + off);    off = align256(off + (size_t)N * DD * 2);
    ushort* hB = (ushort*)(ws + off);    off = align256(off + (size_t)N * DD * 2);
    ushort* zb = (ushort*)(ws + off);    off = align256(off + (size_t)N * DD * 2);
    float* Wp = (float*)(ws + off);      off = align256(off + (size_t)L * DD * DD * 4);
    (void)ws_size;

    const int mt = (N + M_TILE - 1) / M_TILE;   // 782
    const int gb = (N + 31) / 32;               // 3125 gather blocks

    // ---- CSR build: bucketed counting sort (no random sub-line stores) ----
    init_bcur<<<(nbuk + 255) / 256, 256, 0, stream>>>(bcur, nbuk);
    partition_kernel<<<PART_BLOCKS, PART_THREADS, 0, stream>>>(row, col, ew, bcur, pk, E, nbuk);
    sort_kernel<<<nbuk, 256, 0, stream>>>(pk, bcur, cw, rowptr2, N);

    // ---- premixed layer weights ----
    int total = L * DD * DD;
    prep_w<<<(total + 255) / 256, 256, 0, stream>>>(conv_w, Wp, total);

    // ---- h0 = relu(x @ Wlin + b) -> x0 (half); layer 0 reads x0 ----
    lin0_kernel<<<mt, 256, 0, stream>>>(x, w_lin, b_lin, x0, N);

    // ---- L layers: gather -> dense. hin: x0, hB, hA, hB; final -> out ----
    for (int l = 0; l < L; ++l) {
        const ushort* hin = (l == 0) ? x0 : ((l % 2 == 1) ? hB : hA);
        ushort* hout      = (l % 2 == 0) ? hB : hA;
        gather_kernel<<<gb, 256, 0, stream>>>(hin, x0, rowptr2, cw, zb, N);
        bool last = (l == L - 1);
        dense_kernel<<<mt, 256, 0, stream>>>(zb, Wp + (size_t)l * DD * DD,
                                             last ? nullptr : hout,
                                             last ? out : nullptr, N);
    }
}

// Round 14
// 300.140 us; speedup vs baseline: 1.1446x; 1.0172x over previous
//
#include <hip/hip_runtime.h>
#include <hip/hip_fp16.h>
#include <math.h>

// GCNII forward, fp16-compressed intermediates.
//   h0 = relu(x @ Wlin + b)                       [lin0: tiled GEMM, M=128]
//   per layer l: h = relu((0.9*(A@h) + 0.1*x0) @ W'_l)   [ONE fused kernel]
//   W'_l = (1-beta_l) I + beta_l W_l (premixed).
// Round-14: dense fused into gather. Per block (32 nodes, 4 waves):
//   phase 1: 8-lane-group gather (round-13 structure: 1KB/instr, padded
//            record slots) -> z in registers -> staged to LDS zs[32][68] f32
//   phase 2: dense from LDS: thread = (node, 8-out slice), W' in LDS
//            (coop-loaded 16KB, pad-68; all patterns <=2-way conflicts=free)
// Eliminates the z global round-trip (25.6MB/layer) + 4 dense dispatches.
// lin0: reg-prefetch dbuf, writes only x0. CSR build: bucketed counting
// sort (no random sub-line global stores).
// Constants: N=100000, E=1600000, H=128, D=64, L=4.

#define DD 64
#define HH 128
#define M_TILE 128
#define K_CHUNK 32
#define NPB 128            // nodes per bucket (bucket = node>>7)
#define SLOT 2560          // record slots per bucket (mean ~2046, +11 sigma)
#define NBUK_MAX 1024
#define PART_BLOCKS 256
#define PART_THREADS 1024
#define GSTRIDE 17         // padded record-slot stride (int2) -> distinct banks
#define WPAD 68            // padded row stride (floats) for Ws/zs

__device__ inline ushort f2h(float f) { return __half_as_ushort(__float2half(f)); }
__device__ inline float us2f(ushort u) { return __half2float(__ushort_as_half(u)); }

__global__ __launch_bounds__(256) void init_bcur(int* bcur, int nbuk) {
    int i = blockIdx.x * blockDim.x + threadIdx.x;
    if (i < nbuk) bcur[i] = i * SLOT;
}

// One-pass partition into bucket slots. Record: {row:17 | col_lo15:15},
// {col_hi2:2 | w_fp16:16<<2}.
__global__ __launch_bounds__(PART_THREADS) void partition_kernel(
    const int* __restrict__ row, const int* __restrict__ col,
    const float* __restrict__ ew, int* __restrict__ bcur,
    uint2* __restrict__ pk, int E, int nbuk) {
    __shared__ int cnt[NBUK_MAX], base[NBUK_MAX], rc[NBUK_MAX];
    int t = threadIdx.x;
    for (int i = t; i < nbuk; i += PART_THREADS) { cnt[i] = 0; rc[i] = 0; }
    __syncthreads();
    int chunk = (E + gridDim.x - 1) / gridDim.x;
    int s0 = blockIdx.x * chunk;
    int s1 = min(s0 + chunk, E);
    for (int e = s0 + t; e < s1; e += PART_THREADS)
        atomicAdd(&cnt[__builtin_nontemporal_load(&row[e]) >> 7], 1);
    __syncthreads();
    for (int i = t; i < nbuk; i += PART_THREADS)
        if (cnt[i] > 0) base[i] = atomicAdd(&bcur[i], cnt[i]);
    __syncthreads();
    for (int e = s0 + t; e < s1; e += PART_THREADS) {
        int r = __builtin_nontemporal_load(&row[e]);
        int c = __builtin_nontemporal_load(&col[e]);
        ushort wh = f2h(__builtin_nontemporal_load(&ew[e]));
        int b = r >> 7;
        int pos = base[b] + atomicAdd(&rc[b], 1);
        if (pos < (b + 1) * SLOT)   // defensive (SLOT is +11 sigma)
            pk[pos] = make_uint2((uint)r | (((uint)c & 0x7fffu) << 17),
                                 ((uint)c >> 15) | ((uint)wh << 2));
    }
}

// Per-bucket counting sort -> CSR segment at cw[b*SLOT ..] + rowptr2 pairs.
__global__ __launch_bounds__(256) void sort_kernel(
    const uint2* __restrict__ pk, const int* __restrict__ bcur,
    int2* __restrict__ cw, int2* __restrict__ rowptr2, int n) {
    __shared__ int hist[NPB], scan[NPB], rc[NPB];
    int b = blockIdx.x, lo = b << 7;
    int cnt = min(bcur[b] - b * SLOT, SLOT);
    const uint2* rec = pk + (size_t)b * SLOT;
    int t = threadIdx.x;
    if (t < NPB) { hist[t] = 0; rc[t] = 0; }
    __syncthreads();
    for (int i = t; i < cnt; i += 256)
        atomicAdd(&hist[(rec[i].x & 0x1ffffu) - lo], 1);
    __syncthreads();
    if (t < NPB) scan[t] = hist[t];
    __syncthreads();
    for (int off = 1; off < NPB; off <<= 1) {       // inclusive scan
        int v = (t < NPB && t >= off) ? scan[t - off] : 0;
        __syncthreads();
        if (t < NPB) scan[t] += v;
        __syncthreads();
    }
    if (t < NPB && lo + t < n) {
        int beg = b * SLOT + scan[t] - hist[t];     // exclusive base
        rowptr2[lo + t] = make_int2(beg, beg + hist[t]);
    }
    for (int i = t; i < cnt; i += 256) {
        uint2 r2 = rec[i];
        int nl = (int)(r2.x & 0x1ffffu) - lo;
        int c = (int)((r2.x >> 17) | ((r2.y & 3u) << 15));
        float w = us2f((ushort)((r2.y >> 2) & 0xffffu));
        int pos = (scan[nl] - hist[nl]) + atomicAdd(&rc[nl], 1);
        cw[b * SLOT + pos] = make_int2(c, __float_as_int(w));
    }
}

// W'_l = (1-beta_l) I + beta_l W_l, all L layers at once.
__global__ __launch_bounds__(256) void prep_w(const float* __restrict__ conv_w,
                                              float* __restrict__ Wp, int total) {
    int i = blockIdx.x * blockDim.x + threadIdx.x;
    if (i >= total) return;
    int l = i >> 12;
    int r = i & 4095;
    int d = r >> 6, j = r & 63;
    float beta = logf(0.5f / (float)(l + 1) + 1.0f);
    float v = beta * conv_w[i];
    if (d == j) v += 1.0f - beta;
    Wp[i] = v;
}

// h0 = relu(x @ Wlin + b) -> x0 only (layer-0 reads x0 directly).
// Register-tiled GEMM, thread = 8 nodes x 4 outs, 128-node tile.
// W from global (L1-hot); x tile in 16KB XOR-swizzled LDS; next x tile
// register-prefetched so HBM latency overlaps the 32-k compute.
__global__ __launch_bounds__(256) void lin0_kernel(
    const float* __restrict__ x, const float* __restrict__ Wlin,
    const float* __restrict__ b, ushort* __restrict__ x0, int n) {
    __shared__ float xs[K_CHUNK][M_TILE];      // 16 KB, swizzled columns
    int t = threadIdx.x;
    int tm = t >> 4, tn = t & 15;
    int m0 = blockIdx.x * M_TILE;

    float4 bb = *(const float4*)&b[tn * 4];
    float acc[8][4];
#pragma unroll
    for (int mi = 0; mi < 8; ++mi) {
        acc[mi][0] = bb.x; acc[mi][1] = bb.y; acc[mi][2] = bb.z; acc[mi][3] = bb.w;
    }

    // prefetch kk = 0
    float4 v[4];
#pragma unroll
    for (int i = 0; i < 4; ++i) {
        int s = t + i * 256;
        int node = s >> 3, cpos = (s & 7) * 4;
        int g = m0 + node;
        v[i] = (g < n) ? *(const float4*)&x[(size_t)g * HH + cpos]
                       : make_float4(0.f, 0.f, 0.f, 0.f);
    }

    for (int kk = 0; kk < HH; kk += K_CHUNK) {
        __syncthreads();                       // prev compute done
#pragma unroll
        for (int i = 0; i < 4; ++i) {
            int s = t + i * 256;
            int node = s >> 3, cpos = (s & 7) * 4;
            int q = (s & 7) & 3;
            int pc = node ^ (q << 3);          // swizzled column
            xs[cpos + 0][pc] = v[i].x;
            xs[cpos + 1][pc] = v[i].y;
            xs[cpos + 2][pc] = v[i].z;
            xs[cpos + 3][pc] = v[i].w;
        }
        __syncthreads();
        if (kk + K_CHUNK < HH) {               // prefetch next tile
#pragma unroll
            for (int i = 0; i < 4; ++i) {
                int s = t + i * 256;
                int node = s >> 3, cpos = (s & 7) * 4;
                int g = m0 + node;
                v[i] = (g < n)
                    ? *(const float4*)&x[(size_t)g * HH + kk + K_CHUNK + cpos]
                    : make_float4(0.f, 0.f, 0.f, 0.f);
            }
        }
#pragma unroll
        for (int k = 0; k < K_CHUNK; ++k) {
            float4 wv = *(const float4*)&Wlin[(size_t)(kk + k) * DD + tn * 4];
            int base = (tm * 8) ^ ((((k) >> 2) & 3) << 3);
            float4 xa = *(const float4*)&xs[k][base];
            float4 xb = *(const float4*)&xs[k][base + 4];
            float xm[8] = {xa.x, xa.y, xa.z, xa.w, xb.x, xb.y, xb.z, xb.w};
            float wj[4] = {wv.x, wv.y, wv.z, wv.w};
#pragma unroll
            for (int mi = 0; mi < 8; ++mi)
#pragma unroll
                for (int j = 0; j < 4; ++j)
                    acc[mi][j] += xm[mi] * wj[j];
        }
    }
#pragma unroll
    for (int mi = 0; mi < 8; ++mi) {
        int node = m0 + tm * 8 + mi;
        if (node >= n) continue;
        ushort4 o;
        o.x = f2h(fmaxf(acc[mi][0], 0.f));
        o.y = f2h(fmaxf(acc[mi][1], 0.f));
        o.z = f2h(fmaxf(acc[mi][2], 0.f));
        o.w = f2h(fmaxf(acc[mi][3], 0.f));
        *(ushort4*)&x0[(size_t)node * DD + tn * 4] = o;
    }
}

// Fused GCNII layer: z = 0.9*(A@h) + 0.1*x0 (gather, registers) ->
// LDS zs -> h = relu(z @ W') (dense from LDS). Block = 32 nodes, 4 waves.
__global__ __launch_bounds__(256) void layer_kernel(
    const ushort* __restrict__ h_in, const ushort* __restrict__ x0,
    const int2* __restrict__ rowptr2, const int2* __restrict__ cw,
    const float* __restrict__ Wp, ushort* __restrict__ h_half,
    float* __restrict__ h_f32, int n) {
    __shared__ float Ws[DD][WPAD];        // 17.4 KB premixed W'
    __shared__ float zs[32][WPAD];        // 8.7 KB z staging
    __shared__ int2 es[4][8 * GSTRIDE];   // 4.3 KB edge records
    int t = threadIdx.x;

    // cooperative W' load: 4096 floats, 16 per thread
    {
        int k = t >> 2, j0 = (t & 3) * 16;
#pragma unroll
        for (int p = 0; p < 4; ++p)
            *(float4*)&Ws[k][j0 + p * 4] =
                *(const float4*)&Wp[(size_t)k * DD + j0 + p * 4];
    }

    // ---- phase 1: gather (8-lane group per node, 8 nodes/wave) ----
    int wave = t >> 6, lane = t & 63;
    int grp = lane >> 3, sub = lane & 7;
    int2* slot = &es[wave][grp * GSTRIDE];
    int ln = wave * 8 + grp;                   // block-local node 0..31
    int node = blockIdx.x * 32 + ln;
    bool nvalid = node < n;
    int nn = nvalid ? node : (n - 1);
    int2 rp = rowptr2[nn];
    int beg = rp.x;
    int end = nvalid ? rp.y : beg;
    uint4 x0v = *(const uint4*)&x0[(size_t)nn * DD + sub * 8];

    float acc[4][8];
#pragma unroll
    for (int c = 0; c < 4; ++c)
#pragma unroll
        for (int f = 0; f < 8; ++f) acc[c][f] = 0.f;

    for (int base = beg; base < end; base += 16) {
        int m = end - base;
        if (m > 16) m = 16;
        if (sub < m) slot[sub] = cw[base + sub];
        if (sub + 8 < m) slot[sub + 8] = cw[base + sub + 8];
        // same-wave LDS write->read; compiler orders via lgkmcnt
#pragma unroll
        for (int j = 0; j < 4; ++j) {
#pragma unroll
            for (int c = 0; c < 4; ++c) {
                int idx = j * 4 + c;
                bool vld = idx < m;
                int2 r = slot[vld ? idx : 0];
                float w = vld ? __int_as_float(r.y) : 0.f;
                uint4 hv = *(const uint4*)&h_in[(size_t)r.x * DD + sub * 8];
                acc[c][0] += w * us2f((ushort)(hv.x & 0xffff));
                acc[c][1] += w * us2f((ushort)(hv.x >> 16));
                acc[c][2] += w * us2f((ushort)(hv.y & 0xffff));
                acc[c][3] += w * us2f((ushort)(hv.y >> 16));
                acc[c][4] += w * us2f((ushort)(hv.z & 0xffff));
                acc[c][5] += w * us2f((ushort)(hv.z >> 16));
                acc[c][6] += w * us2f((ushort)(hv.w & 0xffff));
                acc[c][7] += w * us2f((ushort)(hv.w >> 16));
            }
        }
    }
    {
        uint xp[4] = {x0v.x, x0v.y, x0v.z, x0v.w};
        float4 za, zb2;
        float* zo[2] = {&za.x, &zb2.x};
#pragma unroll
        for (int k = 0; k < 8; ++k) {
            float f = (acc[0][k] + acc[1][k]) + (acc[2][k] + acc[3][k]);
            float xv = (k & 1) ? us2f((ushort)(xp[k >> 1] >> 16))
                               : us2f((ushort)(xp[k >> 1] & 0xffff));
            zo[k >> 2][k & 3] = 0.9f * f + 0.1f * xv;
        }
        *(float4*)&zs[ln][sub * 8] = za;
        *(float4*)&zs[ln][sub * 8 + 4] = zb2;
    }
    __syncthreads();

    // ---- phase 2: dense h = relu(z @ W') ----
    int ln2 = t >> 3, tn = t & 7;
    int gnode = blockIdx.x * 32 + ln2;
    float o[8];
#pragma unroll
    for (int j = 0; j < 8; ++j) o[j] = 0.f;
#pragma unroll
    for (int k = 0; k < DD; ++k) {
        float zk = zs[ln2][k];                 // broadcast within 8 threads
        float4 wa = *(const float4*)&Ws[k][tn * 8];
        float4 wb = *(const float4*)&Ws[k][tn * 8 + 4];
        o[0] += zk * wa.x; o[1] += zk * wa.y;
        o[2] += zk * wa.z; o[3] += zk * wa.w;
        o[4] += zk * wb.x; o[5] += zk * wb.y;
        o[6] += zk * wb.z; o[7] += zk * wb.w;
    }
    if (gnode < n) {
#pragma unroll
        for (int j = 0; j < 8; ++j) o[j] = fmaxf(o[j], 0.f);
        if (h_f32) {
            *(float4*)&h_f32[(size_t)gnode * DD + tn * 8] =
                make_float4(o[0], o[1], o[2], o[3]);
            *(float4*)&h_f32[(size_t)gnode * DD + tn * 8 + 4] =
                make_float4(o[4], o[5], o[6], o[7]);
        } else {
            uint4 ov;
            ov.x = (uint)f2h(o[0]) | ((uint)f2h(o[1]) << 16);
            ov.y = (uint)f2h(o[2]) | ((uint)f2h(o[3]) << 16);
            ov.z = (uint)f2h(o[4]) | ((uint)f2h(o[5]) << 16);
            ov.w = (uint)f2h(o[6]) | ((uint)f2h(o[7]) << 16);
            *(uint4*)&h_half[(size_t)gnode * DD + tn * 8] = ov;
        }
    }
}

static inline size_t align256(size_t x) { return (x + 255) & ~(size_t)255; }

extern "C" void kernel_launch(void* const* d_in, const int* in_sizes, int n_in,
                              void* d_out, int out_size, void* d_ws, size_t ws_size,
                              hipStream_t stream) {
    const float* x      = (const float*)d_in[0];
    const int*   row    = (const int*)d_in[1];
    const int*   col    = (const int*)d_in[2];
    const float* ew     = (const float*)d_in[3];
    const float* w_lin  = (const float*)d_in[4];
    const float* b_lin  = (const float*)d_in[5];
    const float* conv_w = (const float*)d_in[6];
    float* out = (float*)d_out;

    const int N = in_sizes[0] / HH;          // 100000
    const int E = in_sizes[1];               // 1600000
    const int L = in_sizes[6] / (DD * DD);   // 4
    const int nbuk = (N + NPB - 1) / NPB;    // 782

    char* ws = (char*)d_ws;
    size_t off = 0;
    int* bcur = (int*)(ws + off);        off = align256(off + (size_t)NBUK_MAX * 4);
    uint2* pk = (uint2*)(ws + off);      off = align256(off + (size_t)nbuk * SLOT * 8);
    int2* cw = (int2*)(ws + off);        off = align256(off + (size_t)nbuk * SLOT * 8);
    int2* rowptr2 = (int2*)(ws + off);   off = align256(off + (size_t)N * 8);
    ushort* x0 = (ushort*)(ws + off);    off = align256(off + (size_t)N * DD * 2);
    ushort* hA = (ushort*)(ws + off);    off = align256(off + (size_t)N * DD * 2);
    ushort* hB = (ushort*)(ws + off);    off = align256(off + (size_t)N * DD * 2);
    float* Wp = (float*)(ws + off);      off = align256(off + (size_t)L * DD * DD * 4);
    (void)ws_size;

    const int mt = (N + M_TILE - 1) / M_TILE;   // 782
    const int gb = (N + 31) / 32;               // 3125 layer blocks

    // ---- CSR build: bucketed counting sort (no random sub-line stores) ----
    init_bcur<<<(nbuk + 255) / 256, 256, 0, stream>>>(bcur, nbuk);
    partition_kernel<<<PART_BLOCKS, PART_THREADS, 0, stream>>>(row, col, ew, bcur, pk, E, nbuk);
    sort_kernel<<<nbuk, 256, 0, stream>>>(pk, bcur, cw, rowptr2, N);

    // ---- premixed layer weights ----
    int total = L * DD * DD;
    prep_w<<<(total + 255) / 256, 256, 0, stream>>>(conv_w, Wp, total);

    // ---- h0 = relu(x @ Wlin + b) -> x0 (half); layer 0 reads x0 ----
    lin0_kernel<<<mt, 256, 0, stream>>>(x, w_lin, b_lin, x0, N);

    // ---- L fused layers. hin: x0, hB, hA, hB; final -> f32 out ----
    for (int l = 0; l < L; ++l) {
        const ushort* hin = (l == 0) ? x0 : ((l % 2 == 1) ? hB : hA);
        ushort* hout      = (l % 2 == 0) ? hB : hA;
        bool last = (l == L - 1);
        layer_kernel<<<gb, 256, 0, stream>>>(hin, x0, rowptr2, cw,
                                             Wp + (size_t)l * DD * DD,
                                             last ? nullptr : hout,
                                             last ? out : nullptr, N);
    }
}